// Round 1
// baseline (50.896 us; speedup 1.0000x reference)
//
#include <hip/hip_runtime.h>

// Segment-mean over contiguous segments.
// x: [N=262144, 256] f32, sizes: [4096] i32 (sum = N), out: [4096, 256] f32.
// Memory-bound: ~260 MB of traffic, roofline ~41 us @ 6.3 TB/s.

#define NSEG 4096

// ---------------------------------------------------------------------------
// Kernel 1: exclusive prefix sum of sizes -> offsets (single block, 256 thr).
// Each thread scans a chunk of 16 in registers, then a Hillis-Steele scan of
// the 256 thread-sums in LDS.
// ---------------------------------------------------------------------------
__global__ __launch_bounds__(256) void scan_offsets_kernel(
    const int* __restrict__ sizes, int* __restrict__ offsets) {
    const int CHUNK = NSEG / 256;  // 16
    int tid = threadIdx.x;
    int base = tid * CHUNK;

    int local[CHUNK];
    int sum = 0;
#pragma unroll
    for (int i = 0; i < CHUNK; ++i) local[i] = sizes[base + i];
#pragma unroll
    for (int i = 0; i < CHUNK; ++i) {
        int v = local[i];
        local[i] = sum;   // exclusive within chunk
        sum += v;
    }

    __shared__ int sh[256];
    sh[tid] = sum;
    __syncthreads();
    for (int off = 1; off < 256; off <<= 1) {
        int v = (tid >= off) ? sh[tid - off] : 0;
        __syncthreads();
        sh[tid] += v;
        __syncthreads();
    }
    int excl = (tid == 0) ? 0 : sh[tid - 1];
#pragma unroll
    for (int i = 0; i < CHUNK; ++i) offsets[base + i] = excl + local[i];
}

// ---------------------------------------------------------------------------
// Kernel 2: one block per segment. tx in [0,64) owns a float4 column,
// ty in [0,4) strides rows. Coalesced 1 KiB/wave row reads, LDS reduce,
// one float4 store per tx.
// ---------------------------------------------------------------------------
__global__ __launch_bounds__(256) void seg_mean_kernel(
    const float* __restrict__ x,
    const int* __restrict__ sizes,
    const int* __restrict__ offsets,
    float* __restrict__ out) {
    int b = blockIdx.x;
    int size = sizes[b];
    size_t start = (size_t)offsets[b];

    int tx = threadIdx.x & 63;   // float4 column
    int ty = threadIdx.x >> 6;   // row phase (0..3)

    const float4* xr = reinterpret_cast<const float4*>(x) + start * 64 + tx;

    float4 a0 = make_float4(0.f, 0.f, 0.f, 0.f);
    float4 a1 = make_float4(0.f, 0.f, 0.f, 0.f);

    int r = ty;
    // two independent loads in flight per thread
    for (; r + 8 <= size; r += 8) {
        float4 v0 = xr[(size_t)r * 64];
        float4 v1 = xr[(size_t)(r + 4) * 64];
        a0.x += v0.x; a0.y += v0.y; a0.z += v0.z; a0.w += v0.w;
        a1.x += v1.x; a1.y += v1.y; a1.z += v1.z; a1.w += v1.w;
    }
    for (; r < size; r += 4) {
        float4 v0 = xr[(size_t)r * 64];
        a0.x += v0.x; a0.y += v0.y; a0.z += v0.z; a0.w += v0.w;
    }
    a0.x += a1.x; a0.y += a1.y; a0.z += a1.z; a0.w += a1.w;

    __shared__ float4 sh[256];
    sh[threadIdx.x] = a0;
    __syncthreads();

    if (ty == 0) {
        float4 b0 = sh[tx];
        float4 b1 = sh[tx + 64];
        float4 b2 = sh[tx + 128];
        float4 b3 = sh[tx + 192];
        float fs = (float)size;
        float4 o;
        o.x = (b0.x + b1.x + b2.x + b3.x) / fs;
        o.y = (b0.y + b1.y + b2.y + b3.y) / fs;
        o.z = (b0.z + b1.z + b2.z + b3.z) / fs;
        o.w = (b0.w + b1.w + b2.w + b3.w) / fs;
        reinterpret_cast<float4*>(out)[(size_t)b * 64 + tx] = o;
    }
}

extern "C" void kernel_launch(void* const* d_in, const int* in_sizes, int n_in,
                              void* d_out, int out_size, void* d_ws, size_t ws_size,
                              hipStream_t stream) {
    const float* x = (const float*)d_in[0];
    const int* sizes = (const int*)d_in[1];
    float* out = (float*)d_out;
    int* offsets = (int*)d_ws;  // 4096 * 4 B = 16 KiB scratch

    scan_offsets_kernel<<<1, 256, 0, stream>>>(sizes, offsets);
    seg_mean_kernel<<<NSEG, 256, 0, stream>>>(x, sizes, offsets, out);
}

// Round 3
// 48.412 us; speedup vs baseline: 1.0513x; 1.0513x over previous
//
#include <hip/hip_runtime.h>

// Segment-mean over contiguous segments (fused single kernel).
// x: [N=262144, 256] f32, sizes: [4096] i32 (sum = N), out: [4096, 256] f32.
// Memory-bound: ~260 MB of traffic; memset on this chip proves ~7 TB/s,
// so target ~40 us.

#define NSEG 4096

// native vector type — required for __builtin_nontemporal_* (HIP float4 is a
// struct and is rejected by the builtin)
typedef float f32x4 __attribute__((ext_vector_type(4)));

__global__ __launch_bounds__(256) void seg_mean_fused_kernel(
    const float* __restrict__ x,
    const int* __restrict__ sizes,
    float* __restrict__ out) {
    const int b   = blockIdx.x;
    const int tid = threadIdx.x;
    const int tx  = tid & 63;   // f32x4 column
    const int ty  = tid >> 6;   // wave id / row phase (0..3)

    // ---- per-block exclusive offset: sum of sizes[0..b) --------------------
    // sizes is 16 KiB -> L1/L2-resident; <=16 strided loads/thread.
    int partial = 0;
    for (int i = tid; i < b; i += 256) partial += sizes[i];
#pragma unroll
    for (int off = 32; off > 0; off >>= 1)
        partial += __shfl_down(partial, off, 64);

    __shared__ int swave[4];
    __shared__ int s_start;
    if (tx == 0) swave[ty] = partial;
    __syncthreads();
    if (tid == 0) s_start = swave[0] + swave[1] + swave[2] + swave[3];
    __syncthreads();

    const int size     = sizes[b];
    const size_t start = (size_t)s_start;

    // ---- streaming reduction: wave ty covers rows ty, ty+4, ty+8, ... ------
    // Each row read is 64 lanes x 16 B = 1 KiB contiguous. 4 loads in flight.
    const f32x4* xr = reinterpret_cast<const f32x4*>(x) + start * 64 + tx;

    f32x4 a0 = {0.f, 0.f, 0.f, 0.f};
    f32x4 a1 = {0.f, 0.f, 0.f, 0.f};
    f32x4 a2 = {0.f, 0.f, 0.f, 0.f};
    f32x4 a3 = {0.f, 0.f, 0.f, 0.f};

    int r = ty;
    for (; r + 16 <= size; r += 16) {
        f32x4 v0 = __builtin_nontemporal_load(&xr[(size_t)r * 64]);
        f32x4 v1 = __builtin_nontemporal_load(&xr[(size_t)(r + 4) * 64]);
        f32x4 v2 = __builtin_nontemporal_load(&xr[(size_t)(r + 8) * 64]);
        f32x4 v3 = __builtin_nontemporal_load(&xr[(size_t)(r + 12) * 64]);
        a0 += v0;
        a1 += v1;
        a2 += v2;
        a3 += v3;
    }
    for (; r < size; r += 4) {
        f32x4 v0 = __builtin_nontemporal_load(&xr[(size_t)r * 64]);
        a0 += v0;
    }
    a0 += a1;
    a2 += a3;
    a0 += a2;

    // ---- cross-wave reduce + mean + store ----------------------------------
    __shared__ f32x4 sh[256];
    sh[tid] = a0;
    __syncthreads();

    if (ty == 0) {
        f32x4 s = sh[tx] + sh[tx + 64] + sh[tx + 128] + sh[tx + 192];
        float fs = (float)size;
        f32x4 o = s / fs;
        __builtin_nontemporal_store(o, &reinterpret_cast<f32x4*>(out)[(size_t)b * 64 + tx]);
    }
}

extern "C" void kernel_launch(void* const* d_in, const int* in_sizes, int n_in,
                              void* d_out, int out_size, void* d_ws, size_t ws_size,
                              hipStream_t stream) {
    const float* x = (const float*)d_in[0];
    const int* sizes = (const int*)d_in[1];
    float* out = (float*)d_out;

    seg_mean_fused_kernel<<<NSEG, 256, 0, stream>>>(x, sizes, out);
}

// Round 4
// 47.793 us; speedup vs baseline: 1.0649x; 1.0129x over previous
//
#include <hip/hip_runtime.h>

// Segment-mean over contiguous segments (fused single kernel).
// x: [N=262144, 256] f32, sizes: [4096] i32 (sum = N), out: [4096, 256] f32.
// Memory-bound: ~260 MB of traffic; float4-copy ceiling ~6.3 TB/s -> ~41 us.

#define NSEG 4096

// native vector types — required for __builtin_nontemporal_* and for
// guaranteed dwordx4 loads
typedef float f32x4 __attribute__((ext_vector_type(4)));
typedef int   i32x4 __attribute__((ext_vector_type(4)));

__global__ __launch_bounds__(256) void seg_mean_fused_kernel(
    const float* __restrict__ x,
    const int* __restrict__ sizes,
    float* __restrict__ out) {
    const int b   = blockIdx.x;
    const int tid = threadIdx.x;
    const int tx  = tid & 63;   // f32x4 column
    const int ty  = tid >> 6;   // wave id / row phase (0..3)

    // ---- per-block exclusive offset: sum of sizes[0..b) --------------------
    // Vectorized: 4 independent dwordx4 loads per thread (compile-time trip
    // count -> fully pipelined), per-element predication for the boundary.
    const i32x4* s4 = reinterpret_cast<const i32x4*>(sizes);
    int partial = 0;
#pragma unroll
    for (int k = 0; k < 4; ++k) {
        int c  = tid + k * 256;   // int4 chunk index, covers [0, 1024)
        int j0 = c * 4;           // first element index of this chunk
        if (j0 < b) {
            i32x4 v = s4[c];
            partial += (j0 + 0 < b) ? v.x : 0;
            partial += (j0 + 1 < b) ? v.y : 0;
            partial += (j0 + 2 < b) ? v.z : 0;
            partial += (j0 + 3 < b) ? v.w : 0;
        }
    }
#pragma unroll
    for (int off = 32; off > 0; off >>= 1)
        partial += __shfl_down(partial, off, 64);

    __shared__ int swave[4];
    __shared__ int s_start;
    if (tx == 0) swave[ty] = partial;
    __syncthreads();
    if (tid == 0) s_start = swave[0] + swave[1] + swave[2] + swave[3];
    __syncthreads();

    const int size     = sizes[b];
    const size_t start = (size_t)s_start;

    // ---- streaming reduction: wave ty covers rows ty, ty+4, ty+8, ... ------
    // Each row read is 64 lanes x 16 B = 1 KiB contiguous. 4 loads in flight.
    const f32x4* xr = reinterpret_cast<const f32x4*>(x) + start * 64 + tx;

    f32x4 a0 = {0.f, 0.f, 0.f, 0.f};
    f32x4 a1 = {0.f, 0.f, 0.f, 0.f};
    f32x4 a2 = {0.f, 0.f, 0.f, 0.f};
    f32x4 a3 = {0.f, 0.f, 0.f, 0.f};

    int r = ty;
    for (; r + 16 <= size; r += 16) {
        f32x4 v0 = __builtin_nontemporal_load(&xr[(size_t)r * 64]);
        f32x4 v1 = __builtin_nontemporal_load(&xr[(size_t)(r + 4) * 64]);
        f32x4 v2 = __builtin_nontemporal_load(&xr[(size_t)(r + 8) * 64]);
        f32x4 v3 = __builtin_nontemporal_load(&xr[(size_t)(r + 12) * 64]);
        a0 += v0;
        a1 += v1;
        a2 += v2;
        a3 += v3;
    }
    for (; r < size; r += 4) {
        f32x4 v0 = __builtin_nontemporal_load(&xr[(size_t)r * 64]);
        a0 += v0;
    }
    a0 += a1;
    a2 += a3;
    a0 += a2;

    // ---- cross-wave reduce + mean + store ----------------------------------
    __shared__ f32x4 sh[256];
    sh[tid] = a0;
    __syncthreads();

    if (ty == 0) {
        f32x4 s = sh[tx] + sh[tx + 64] + sh[tx + 128] + sh[tx + 192];
        float fs = (float)size;
        f32x4 o = s / fs;
        __builtin_nontemporal_store(o, &reinterpret_cast<f32x4*>(out)[(size_t)b * 64 + tx]);
    }
}

extern "C" void kernel_launch(void* const* d_in, const int* in_sizes, int n_in,
                              void* d_out, int out_size, void* d_ws, size_t ws_size,
                              hipStream_t stream) {
    const float* x = (const float*)d_in[0];
    const int* sizes = (const int*)d_in[1];
    float* out = (float*)d_out;

    seg_mean_fused_kernel<<<NSEG, 256, 0, stream>>>(x, sizes, out);
}

// Round 5
// 47.706 us; speedup vs baseline: 1.0669x; 1.0018x over previous
//
#include <hip/hip_runtime.h>

// Segment-mean over contiguous segments — one WAVE per segment.
// x: [N=262144, 256] f32, sizes: [4096] i32 (sum = N), out: [4096, 256] f32.
// Memory-bound: ~260 MB; target ~41-44 us (~6.3 TB/s read stream).
//
// Layout: block = 256 threads = 4 waves; block b owns segments 4b..4b+3,
// wave w handles segment 4b+w entirely. Lane tx accumulates column slice
// [tx*4, tx*4+4) across all rows -> accumulation is lane-local (no LDS
// reduce, no epilogue barrier). Each wave streams a contiguous region,
// 4 KiB per unrolled iteration.

#define NSEG 4096

typedef float f32x4 __attribute__((ext_vector_type(4)));
typedef int   i32x4 __attribute__((ext_vector_type(4)));

__global__ __launch_bounds__(256) void seg_mean_wave_kernel(
    const float* __restrict__ x,
    const int* __restrict__ sizes,
    float* __restrict__ out) {
    const int b   = blockIdx.x;        // 0..1023
    const int tid = threadIdx.x;
    const int tx  = tid & 63;          // lane
    const int w   = tid >> 6;          // wave id = segment within block
    const int g0  = b * 4;             // first segment of this block

    // ---- block-level scan: base = sum sizes[0..g0) -------------------------
    // g0 % 4 == 0, so chunk-level predicate (c < b) is exact: chunk c covers
    // elements 4c..4c+3. 4 independent dwordx4 loads per thread.
    const i32x4* s4 = reinterpret_cast<const i32x4*>(sizes);
    int partial = 0;
#pragma unroll
    for (int k = 0; k < 4; ++k) {
        int c = tid + k * 256;          // chunk index in [0, 1024)
        if (c < b) {
            i32x4 v = s4[c];
            partial += v.x + v.y + v.z + v.w;
        }
    }
#pragma unroll
    for (int off = 32; off > 0; off >>= 1)
        partial += __shfl_down(partial, off, 64);

    __shared__ int swave[4];
    if (tx == 0) swave[w] = partial;
    __syncthreads();
    const int base = swave[0] + swave[1] + swave[2] + swave[3];

    // ---- per-wave segment offset (wave-uniform) ----------------------------
    i32x4 ls = s4[b];                   // sizes[g0..g0+3]
    int off = base;
    if (w > 0) off += ls.x;
    if (w > 1) off += ls.y;
    if (w > 2) off += ls.z;
    const int sz = (w == 0) ? ls.x : (w == 1) ? ls.y : (w == 2) ? ls.z : ls.w;
    const int seg = g0 + w;

    // ---- contiguous stream: rows 0..sz-1, 4 rows (4 KiB) per iteration -----
    const f32x4* p = reinterpret_cast<const f32x4*>(x) + (size_t)off * 64 + tx;

    f32x4 a0 = {0.f, 0.f, 0.f, 0.f};
    f32x4 a1 = {0.f, 0.f, 0.f, 0.f};
    f32x4 a2 = {0.f, 0.f, 0.f, 0.f};
    f32x4 a3 = {0.f, 0.f, 0.f, 0.f};

    int r = 0;
    for (; r + 4 <= sz; r += 4) {
        f32x4 v0 = __builtin_nontemporal_load(&p[(r + 0) * 64]);
        f32x4 v1 = __builtin_nontemporal_load(&p[(r + 1) * 64]);
        f32x4 v2 = __builtin_nontemporal_load(&p[(r + 2) * 64]);
        f32x4 v3 = __builtin_nontemporal_load(&p[(r + 3) * 64]);
        a0 += v0;
        a1 += v1;
        a2 += v2;
        a3 += v3;
    }
    for (; r < sz; ++r)
        a0 += __builtin_nontemporal_load(&p[r * 64]);

    a0 += a1;
    a2 += a3;
    a0 += a2;

    f32x4 o = a0 / (float)sz;
    __builtin_nontemporal_store(o, &reinterpret_cast<f32x4*>(out)[(size_t)seg * 64 + tx]);
}

extern "C" void kernel_launch(void* const* d_in, const int* in_sizes, int n_in,
                              void* d_out, int out_size, void* d_ws, size_t ws_size,
                              hipStream_t stream) {
    const float* x = (const float*)d_in[0];
    const int* sizes = (const int*)d_in[1];
    float* out = (float*)d_out;

    seg_mean_wave_kernel<<<NSEG / 4, 256, 0, stream>>>(x, sizes, out);
}

// Round 6
// 47.485 us; speedup vs baseline: 1.0718x; 1.0047x over previous
//
#include <hip/hip_runtime.h>

// Segment-mean over contiguous segments — one WAVE per segment.
// x: [N=262144, 256] f32, sizes: [4096] i32 (sum = N), out: [4096, 256] f32.
// Round 6: nt-load ABLATION — identical to round 5 but with plain (cached)
// loads/stores instead of __builtin_nontemporal_*. Single-axis probe of the
// TCC cache-policy cost.

#define NSEG 4096

typedef float f32x4 __attribute__((ext_vector_type(4)));
typedef int   i32x4 __attribute__((ext_vector_type(4)));

__global__ __launch_bounds__(256) void seg_mean_wave_kernel(
    const float* __restrict__ x,
    const int* __restrict__ sizes,
    float* __restrict__ out) {
    const int b   = blockIdx.x;        // 0..1023
    const int tid = threadIdx.x;
    const int tx  = tid & 63;          // lane
    const int w   = tid >> 6;          // wave id = segment within block
    const int g0  = b * 4;             // first segment of this block

    // ---- block-level scan: base = sum sizes[0..g0) -------------------------
    const i32x4* s4 = reinterpret_cast<const i32x4*>(sizes);
    int partial = 0;
#pragma unroll
    for (int k = 0; k < 4; ++k) {
        int c = tid + k * 256;          // chunk index in [0, 1024)
        if (c < b) {
            i32x4 v = s4[c];
            partial += v.x + v.y + v.z + v.w;
        }
    }
#pragma unroll
    for (int off = 32; off > 0; off >>= 1)
        partial += __shfl_down(partial, off, 64);

    __shared__ int swave[4];
    if (tx == 0) swave[w] = partial;
    __syncthreads();
    const int base = swave[0] + swave[1] + swave[2] + swave[3];

    // ---- per-wave segment offset (wave-uniform) ----------------------------
    i32x4 ls = s4[b];                   // sizes[g0..g0+3]
    int off = base;
    if (w > 0) off += ls.x;
    if (w > 1) off += ls.y;
    if (w > 2) off += ls.z;
    const int sz = (w == 0) ? ls.x : (w == 1) ? ls.y : (w == 2) ? ls.z : ls.w;
    const int seg = g0 + w;

    // ---- contiguous stream: rows 0..sz-1, 4 rows (4 KiB) per iteration -----
    const f32x4* p = reinterpret_cast<const f32x4*>(x) + (size_t)off * 64 + tx;

    f32x4 a0 = {0.f, 0.f, 0.f, 0.f};
    f32x4 a1 = {0.f, 0.f, 0.f, 0.f};
    f32x4 a2 = {0.f, 0.f, 0.f, 0.f};
    f32x4 a3 = {0.f, 0.f, 0.f, 0.f};

    int r = 0;
    for (; r + 4 <= sz; r += 4) {
        f32x4 v0 = p[(r + 0) * 64];
        f32x4 v1 = p[(r + 1) * 64];
        f32x4 v2 = p[(r + 2) * 64];
        f32x4 v3 = p[(r + 3) * 64];
        a0 += v0;
        a1 += v1;
        a2 += v2;
        a3 += v3;
    }
    for (; r < sz; ++r)
        a0 += p[r * 64];

    a0 += a1;
    a2 += a3;
    a0 += a2;

    f32x4 o = a0 / (float)sz;
    reinterpret_cast<f32x4*>(out)[(size_t)seg * 64 + tx] = o;
}

extern "C" void kernel_launch(void* const* d_in, const int* in_sizes, int n_in,
                              void* d_out, int out_size, void* d_ws, size_t ws_size,
                              hipStream_t stream) {
    const float* x = (const float*)d_in[0];
    const int* sizes = (const int*)d_in[1];
    float* out = (float*)d_out;

    seg_mean_wave_kernel<<<NSEG / 4, 256, 0, stream>>>(x, sizes, out);
}